// Round 2
// baseline (2597.713 us; speedup 1.0000x reference)
//
#include <hip/hip_runtime.h>
#include <hip/hip_fp16.h>
#include <stdint.h>

#define B_    64
#define T_    512
#define OBS_  128
#define FEAT_ 512
#define H_    256
#define G_    768
#define BT_   32768
#define NA_   10

struct __align__(16) H2x4 { __half2 a, b, c, d; };

__device__ __forceinline__ uint32_t h2u(__half2 h){ union{ __half2 h; uint32_t u; } c; c.h = h; return c.u; }
__device__ __forceinline__ __half2 u2h(uint32_t u){ union{ uint32_t u; __half2 h; } c; c.u = u; return c.h; }

// ---------------------------------------------------------------------------
// GEMM: C[M x N] = act( A[M x K] @ W[N x K]^T + bias ), C rows = A rows.
// M-tile 128, N-tile 128, K-chunk 32. 256 threads, each 8x8 outputs.
// fp16-packed LDS tiles with granule XOR swizzle; half2 accumulators.
// ---------------------------------------------------------------------------
template<int KD, bool AHALF, bool RELU, int ROWH2>
__global__ __launch_bounds__(256, 2)
void gemm_kernel(const float* __restrict__ Af, const __half2* __restrict__ Ah,
                 const float* __restrict__ W, const float* __restrict__ bias,
                 __half2* __restrict__ C)
{
    __shared__ H2x4 As[128 * 4];
    __shared__ H2x4 Bs[128 * 4];
    const int mt = blockIdx.x, nt = blockIdx.y;
    const int m0 = mt * 128, n0 = nt * 128;
    const int tid = threadIdx.x;
    const int r  = tid & 127;            // loader: tile row
    const int gp = (tid >> 7) * 2;       // loader: granule pair base (0 or 2)
    const int tr = tid >> 4, tc = tid & 15;  // compute: 16x16 thread grid

    __half2 acc[8][8];
    const __half2 hz = __float2half2_rn(0.0f);
    #pragma unroll
    for (int i = 0; i < 8; ++i)
        #pragma unroll
        for (int j = 0; j < 8; ++j) acc[i][j] = hz;

    for (int kc = 0; kc < KD / 32; ++kc) {
        __syncthreads();
        const int swz = (r >> 3) & 3;
        // ---- stage A tile ----
        if constexpr (!AHALF) {
            const float* src = Af + (size_t)(m0 + r) * KD + kc * 32 + gp * 8;
            #pragma unroll
            for (int g = 0; g < 2; ++g) {
                float4 f0 = ((const float4*)src)[g * 2 + 0];
                float4 f1 = ((const float4*)src)[g * 2 + 1];
                H2x4 gr;
                gr.a = __floats2half2_rn(f0.x, f0.y);
                gr.b = __floats2half2_rn(f0.z, f0.w);
                gr.c = __floats2half2_rn(f1.x, f1.y);
                gr.d = __floats2half2_rn(f1.z, f1.w);
                As[r * 4 + ((gp + g) ^ swz)] = gr;
            }
        } else {
            const H2x4* src = (const H2x4*)(Ah + (size_t)(m0 + r) * (KD / 2) + kc * 16 + gp * 4);
            #pragma unroll
            for (int g = 0; g < 2; ++g)
                As[r * 4 + ((gp + g) ^ swz)] = src[g];
        }
        // ---- stage B tile (W rows n0+r) ----
        {
            const float* src = W + (size_t)(n0 + r) * KD + kc * 32 + gp * 8;
            #pragma unroll
            for (int g = 0; g < 2; ++g) {
                float4 f0 = ((const float4*)src)[g * 2 + 0];
                float4 f1 = ((const float4*)src)[g * 2 + 1];
                H2x4 gr;
                gr.a = __floats2half2_rn(f0.x, f0.y);
                gr.b = __floats2half2_rn(f0.z, f0.w);
                gr.c = __floats2half2_rn(f1.x, f1.y);
                gr.d = __floats2half2_rn(f1.z, f1.w);
                Bs[r * 4 + ((gp + g) ^ swz)] = gr;
            }
        }
        __syncthreads();
        // ---- compute ----
        #pragma unroll
        for (int ks = 0; ks < 4; ++ks) {
            H2x4 Ag[8], Bg[8];
            #pragma unroll
            for (int i = 0; i < 8; ++i) Ag[i] = As[(tr * 8 + i) * 4 + (ks ^ (tr & 3))];
            #pragma unroll
            for (int j = 0; j < 8; ++j) Bg[j] = Bs[(tc * 8 + j) * 4 + (ks ^ (tc & 3))];
            #pragma unroll
            for (int i = 0; i < 8; ++i)
                #pragma unroll
                for (int j = 0; j < 8; ++j) {
                    acc[i][j] = __hfma2(Ag[i].a, Bg[j].a, acc[i][j]);
                    acc[i][j] = __hfma2(Ag[i].b, Bg[j].b, acc[i][j]);
                    acc[i][j] = __hfma2(Ag[i].c, Bg[j].c, acc[i][j]);
                    acc[i][j] = __hfma2(Ag[i].d, Bg[j].d, acc[i][j]);
                }
        }
    }
    // ---- epilogue ----
    float bj[8];
    #pragma unroll
    for (int j = 0; j < 8; ++j) bj[j] = bias[n0 + tc * 8 + j];
    #pragma unroll
    for (int i = 0; i < 8; ++i) {
        int m = m0 + tr * 8 + i;
        float v[8];
        #pragma unroll
        for (int j = 0; j < 8; ++j) {
            v[j] = __low2float(acc[i][j]) + __high2float(acc[i][j]) + bj[j];
            if (RELU) v[j] = fmaxf(v[j], 0.0f);
        }
        H2x4 o;
        o.a = __floats2half2_rn(v[0], v[1]);
        o.b = __floats2half2_rn(v[2], v[3]);
        o.c = __floats2half2_rn(v[4], v[5]);
        o.d = __floats2half2_rn(v[6], v[7]);
        *((H2x4*)(C + (size_t)m * ROWH2 + (n0 / 2 + tc * 4))) = o;
    }
}

// ---------------------------------------------------------------------------
// Segment builder: masks reset h to 0 (h *= m, m in {0,1}), so the scan
// splits into independent segments starting at s==0 and at every m==0 step.
// One block per batch: flag starts, prefix-scan ranks, scatter positions.
// ---------------------------------------------------------------------------
__global__ __launch_bounds__(512)
void seg_build(const int* __restrict__ masks, int* __restrict__ seg_start,
               int* __restrict__ seg_cnt)
{
    __shared__ int sc[512];
    const int b = blockIdx.x, s = threadIdx.x;
    const int is = (s == 0) || (masks[b * (T_ - 1) + s - 1] == 0);
    sc[s] = is;
    __syncthreads();
    #pragma unroll
    for (int off = 1; off < 512; off <<= 1) {
        int v = (s >= off) ? sc[s - off] : 0;
        __syncthreads();
        sc[s] += v;
        __syncthreads();
    }
    if (is) seg_start[b * 512 + sc[s] - 1] = s;
    if (s == 511) seg_cnt[b] = sc[s];
}

// ---------------------------------------------------------------------------
// Segment-parallel GRU: persistent blocks, W_hh fp16 in registers
// (thread (q=tid>>7, r1=tid&127) holds rows r1+j*128, k-slice [q*64,q*64+64)).
// Each block walks interleaved slots of the (batch x segment) grid.
// First step of a non-t0 segment has h==0 -> gh = b_hh, dot skipped.
// ---------------------------------------------------------------------------
__global__ __launch_bounds__(512, 4)
void gru_seg(const __half2* __restrict__ gx,   // (B*T) x 384 h2, batch-major
             const float* __restrict__ Whh,    // 768 x 256
             const float* __restrict__ bhh,    // 768
             const float* __restrict__ h0,     // B x 256
             const int* __restrict__ seg_start,
             const int* __restrict__ seg_cnt,
             float* __restrict__ hs)           // (B*T) x 256
{
    __shared__ __align__(16) uint32_t h2buf[128];
    __shared__ float part[3072];
    __shared__ int scnt[B_];
    const int tid = threadIdx.x;
    const int q = tid >> 7;        // k-quarter 0..3
    const int r1 = tid & 127;

    // weight registers: 6 outputs x 32 half2 (64 k each)
    __half2 w[6][32];
    #pragma unroll
    for (int j = 0; j < 6; ++j) {
        const float2* wr = (const float2*)(Whh + (size_t)(r1 + j * 128) * 256 + q * 64);
        #pragma unroll
        for (int kk = 0; kk < 32; ++kk) {
            float2 f = wr[kk];
            w[j][kk] = __floats2half2_rn(f.x, f.y);
        }
    }
    float bh_r = 0.f, bh_z = 0.f, bh_n = 0.f;
    if (tid < 256) {
        bh_r = bhh[tid];
        bh_z = bhh[tid + 256];
        bh_n = bhh[tid + 512];
    }
    if (tid < B_) scnt[tid] = seg_cnt[tid];
    __syncthreads();

    const uint4* h2v = (const uint4*)h2buf;
    const __half2 hz = __float2half2_rn(0.0f);

    for (int slot = blockIdx.x; slot < B_ * 512; slot += gridDim.x) {
        const int b = slot >> 9, i0 = slot & 511;
        const int cnt = scnt[b];
        if (i0 >= cnt) continue;
        const int start = seg_start[slot];
        const int nxt = (i0 + 1 < cnt) ? seg_start[slot + 1] : T_;
        const int len = nxt - start;

        float hreg = 0.f;
        if (start == 0) {   // batch-initial segment: h comes from h0, full dot at step 0
            if (tid < 256) hreg = h0[b * 256 + tid];
            if (tid < 128) {
                float2 f = ((const float2*)(h0 + b * 256))[tid];
                h2buf[tid] = h2u(__floats2half2_rn(f.x, f.y));
            }
            __syncthreads();
        }
        // prefetch gx for the first step
        float gxr = 0.f, gxz = 0.f, gxn = 0.f;
        if (tid < 256) {
            const __half* grow = (const __half*)(gx + (size_t)(b * T_ + start) * 384);
            gxr = __half2float(grow[tid]);
            gxz = __half2float(grow[tid + 256]);
            gxn = __half2float(grow[tid + 512]);
        }
        for (int i = 0; i < len; ++i) {
            const bool md = (i > 0) || (start == 0);   // uniform across block
            if (md) {
                __half2 acc0 = hz, acc1 = hz, acc2 = hz, acc3 = hz, acc4 = hz, acc5 = hz;
                #pragma unroll
                for (int kb = 0; kb < 8; ++kb) {
                    uint4 hv = h2v[q * 8 + kb];
                    __half2 e0 = u2h(hv.x), e1 = u2h(hv.y), e2 = u2h(hv.z), e3 = u2h(hv.w);
                    acc0 = __hfma2(w[0][kb*4+0], e0, acc0); acc0 = __hfma2(w[0][kb*4+1], e1, acc0);
                    acc0 = __hfma2(w[0][kb*4+2], e2, acc0); acc0 = __hfma2(w[0][kb*4+3], e3, acc0);
                    acc1 = __hfma2(w[1][kb*4+0], e0, acc1); acc1 = __hfma2(w[1][kb*4+1], e1, acc1);
                    acc1 = __hfma2(w[1][kb*4+2], e2, acc1); acc1 = __hfma2(w[1][kb*4+3], e3, acc1);
                    acc2 = __hfma2(w[2][kb*4+0], e0, acc2); acc2 = __hfma2(w[2][kb*4+1], e1, acc2);
                    acc2 = __hfma2(w[2][kb*4+2], e2, acc2); acc2 = __hfma2(w[2][kb*4+3], e3, acc2);
                    acc3 = __hfma2(w[3][kb*4+0], e0, acc3); acc3 = __hfma2(w[3][kb*4+1], e1, acc3);
                    acc3 = __hfma2(w[3][kb*4+2], e2, acc3); acc3 = __hfma2(w[3][kb*4+3], e3, acc3);
                    acc4 = __hfma2(w[4][kb*4+0], e0, acc4); acc4 = __hfma2(w[4][kb*4+1], e1, acc4);
                    acc4 = __hfma2(w[4][kb*4+2], e2, acc4); acc4 = __hfma2(w[4][kb*4+3], e3, acc4);
                    acc5 = __hfma2(w[5][kb*4+0], e0, acc5); acc5 = __hfma2(w[5][kb*4+1], e1, acc5);
                    acc5 = __hfma2(w[5][kb*4+2], e2, acc5); acc5 = __hfma2(w[5][kb*4+3], e3, acc5);
                }
                part[r1 + 0 * 128 + q * 768] = __low2float(acc0) + __high2float(acc0);
                part[r1 + 1 * 128 + q * 768] = __low2float(acc1) + __high2float(acc1);
                part[r1 + 2 * 128 + q * 768] = __low2float(acc2) + __high2float(acc2);
                part[r1 + 3 * 128 + q * 768] = __low2float(acc3) + __high2float(acc3);
                part[r1 + 4 * 128 + q * 768] = __low2float(acc4) + __high2float(acc4);
                part[r1 + 5 * 128 + q * 768] = __low2float(acc5) + __high2float(acc5);
            }
            // rotate: issue next step's gx load before the barrier+gates
            float nr = 0.f, nz = 0.f, nn = 0.f;
            if (tid < 256 && i + 1 < len) {
                const __half* grow = (const __half*)(gx + (size_t)(b * T_ + start + i + 1) * 384);
                nr = __half2float(grow[tid]);
                nz = __half2float(grow[tid + 256]);
                nn = __half2float(grow[tid + 512]);
            }
            if (md) __syncthreads();
            if (tid < 256) {
                float ghr = bh_r, ghz = bh_z, ghn = bh_n;
                if (md) {
                    ghr += part[tid]       + part[tid + 768]       + part[tid + 1536]       + part[tid + 2304];
                    ghz += part[tid + 256] + part[tid + 256 + 768] + part[tid + 256 + 1536] + part[tid + 256 + 2304];
                    ghn += part[tid + 512] + part[tid + 512 + 768] + part[tid + 512 + 1536] + part[tid + 512 + 2304];
                }
                const float hp = md ? hreg : 0.0f;
                const float rg = 1.0f / (1.0f + exp2f(-(gxr + ghr) * 1.44269504f));
                const float zg = 1.0f / (1.0f + exp2f(-(gxz + ghz) * 1.44269504f));
                const float nin = gxn + rg * ghn;
                const float e2x = exp2f(nin * 2.885390082f);
                const float ng = 1.0f - 2.0f / (e2x + 1.0f);      // tanh(nin)
                const float hnew = (1.0f - zg) * ng + zg * hp;
                hreg = hnew;
                hs[(size_t)(b * T_ + start + i) * 256 + tid] = hnew;
                const float other = __shfl_xor(hnew, 1);
                if ((tid & 1) == 0)
                    h2buf[tid >> 1] = h2u(__floats2half2_rn(hnew, other));
            }
            gxr = nr; gxz = nz; gxn = nn;
            __syncthreads();
        }
    }
}

// ---------------------------------------------------------------------------
// Heads: one wave per output row. 11 dots of 256, butterfly reduce,
// stable log_softmax, entropy, action gather.
// ---------------------------------------------------------------------------
__global__ __launch_bounds__(256)
void heads_kernel(const float* __restrict__ hs, const float* __restrict__ Wa,
                  const float* __restrict__ ba, const float* __restrict__ Wc,
                  const float* __restrict__ bc, const int* __restrict__ action,
                  float* __restrict__ out)
{
    const int wid = threadIdx.x >> 6, lane = threadIdx.x & 63;
    const int row = blockIdx.x * 4 + wid;
    const float4 hv = ((const float4*)(hs + (size_t)row * 256))[lane];
    float sums[11];
    #pragma unroll
    for (int n = 0; n < 11; ++n) {
        const float* wrow = (n < 10) ? (Wa + n * 256) : Wc;
        const float4 wv = ((const float4*)wrow)[lane];
        sums[n] = hv.x * wv.x + hv.y * wv.y + hv.z * wv.z + hv.w * wv.w;
    }
    #pragma unroll
    for (int n = 0; n < 11; ++n) {
        float v = sums[n];
        #pragma unroll
        for (int off = 32; off; off >>= 1) v += __shfl_xor(v, off);
        sums[n] = v;
    }
    float logits[10];
    #pragma unroll
    for (int n = 0; n < 10; ++n) logits[n] = sums[n] + ba[n];
    const float value = sums[10] + bc[0];
    float mx = logits[0];
    #pragma unroll
    for (int n = 1; n < 10; ++n) mx = fmaxf(mx, logits[n]);
    float ssum = 0.f, sdot = 0.f;
    #pragma unroll
    for (int n = 0; n < 10; ++n) {
        float d = logits[n] - mx;
        float e = exp2f(d * 1.44269504f);
        ssum += e; sdot += e * d;
    }
    const float lns = logf(ssum);
    const float lse = mx + lns;
    const float entropy = lns - sdot / ssum;
    const int a = action[row];
    float la = 0.f;
    #pragma unroll
    for (int n = 0; n < 10; ++n) la = (n == a) ? logits[n] : la;
    if (lane == 0) {
        out[row] = value;
        out[BT_ + row] = la - lse;
        out[2 * BT_ + row] = entropy;
    }
}

// ---------------------------------------------------------------------------
extern "C" void kernel_launch(void* const* d_in, const int* in_sizes, int n_in,
                              void* d_out, int out_size, void* d_ws, size_t ws_size,
                              hipStream_t stream)
{
    const float* obs    = (const float*)d_in[0];
    const int*   action = (const int*)d_in[1];
    const int*   masks  = (const int*)d_in[2];
    const float* h0     = (const float*)d_in[3];
    const float* W1     = (const float*)d_in[4];
    const float* b1     = (const float*)d_in[5];
    const float* Wih    = (const float*)d_in[6];
    const float* Whh    = (const float*)d_in[7];
    const float* bih    = (const float*)d_in[8];
    const float* bhh    = (const float*)d_in[9];
    const float* Wa     = (const float*)d_in[10];
    const float* ba     = (const float*)d_in[11];
    const float* Wc     = (const float*)d_in[12];
    const float* bc     = (const float*)d_in[13];
    float* out = (float*)d_out;

    char* ws = (char*)d_ws;
    __half2* feat  = (__half2*)ws;                                  // 33,554,432 B
    __half2* gx    = (__half2*)(ws + 33554432);                     // 50,331,648 B (batch-major)
    float*   hs    = (float*)(ws + 33554432 + 50331648);            // 33,554,432 B
    int*     sstrt = (int*)(ws + 117440512);                        // 131,072 B
    int*     scnt  = (int*)(ws + 117440512 + 131072);               // 256 B

    // segment decomposition of the masked recurrence (independent of GEMMs)
    seg_build<<<B_, 512, 0, stream>>>(masks, sstrt, scnt);
    // feat = relu(obs @ W1^T + b1)
    gemm_kernel<128, false, true,  FEAT_/2><<<dim3(256, 4), 256, 0, stream>>>(obs, nullptr, W1, b1, feat);
    // gx = feat @ W_ih^T + b_ih   (batch-major rows)
    gemm_kernel<512, true,  false, G_/2   ><<<dim3(256, 6), 256, 0, stream>>>(nullptr, feat, Wih, bih, gx);
    // segment-parallel recurrence
    gru_seg<<<512, 512, 0, stream>>>(gx, Whh, bhh, h0, sstrt, scnt, hs);
    // heads
    heads_kernel<<<8192, 256, 0, stream>>>(hs, Wa, ba, Wc, bc, action, out);
}

// Round 3
// 408.722 us; speedup vs baseline: 6.3557x; 6.3557x over previous
//
#include <hip/hip_runtime.h>
#include <hip/hip_fp16.h>
#include <stdint.h>

#define B_    64
#define T_    512
#define OBS_  128
#define FEAT_ 512
#define H_    256
#define G_    768
#define BT_   32768
#define NA_   10

typedef _Float16 f16x8 __attribute__((ext_vector_type(8)));
typedef float    f32x4 __attribute__((ext_vector_type(4)));

__device__ __forceinline__ uint32_t h2u(__half2 h){ union{ __half2 h; uint32_t u; } c; c.h = h; return c.u; }
__device__ __forceinline__ __half2 u2h(uint32_t u){ union{ uint32_t u; __half2 h; } c; c.u = u; return c.h; }

// swizzled LDS byte offset: tile [128 rows][8 chunks of 16B], chunk ^= row&7
// -> 16-lane frag reads hit each bank pair exactly twice (2-way = free, m136)
__device__ __forceinline__ int sw(int r, int c) { return r * 128 + ((c ^ (r & 7)) << 4); }

__device__ __forceinline__ uint4 cvt8(float4 a, float4 b) {
    uint4 u;
    u.x = h2u(__floats2half2_rn(a.x, a.y));
    u.y = h2u(__floats2half2_rn(a.z, a.w));
    u.z = h2u(__floats2half2_rn(b.x, b.y));
    u.w = h2u(__floats2half2_rn(b.z, b.w));
    return u;
}

// ---------------------------------------------------------------------------
// MFMA GEMM: C[M x N](fp16) = act( A[M x K] @ W[N x K]^T + bias )
// 128x128 tile, BK=64, 4 waves (2x2), each wave 4x4 frags of 16x16x32_f16.
// Reg-staged double buffer: next tile's global loads issue before compute.
// ---------------------------------------------------------------------------
template<int KD, bool AF32, bool RELU>
__global__ __launch_bounds__(256, 2)
void mfma_gemm(const float* __restrict__ Af, const __half* __restrict__ Ah,
               const __half* __restrict__ Bh, const float* __restrict__ bias,
               uint32_t* __restrict__ C, int N)
{
    __shared__ __align__(16) __half As[128 * 64];
    __shared__ __align__(16) __half Bs[128 * 64];
    const int m0 = blockIdx.x * 128, n0 = blockIdx.y * 128;
    const int tid = threadIdx.x;
    const int r = tid >> 1, cb = (tid & 1) * 4;        // staging role
    const int lane = tid & 63, w = tid >> 6;           // compute role
    const int wm = w >> 1, wn = w & 1;
    const int l15 = lane & 15, lq = lane >> 4;
    constexpr int KT = KD / 64;

    f32x4 acc[4][4];
    #pragma unroll
    for (int i = 0; i < 4; ++i)
        #pragma unroll
        for (int j = 0; j < 4; ++j) {
            f32x4 z = {0.f, 0.f, 0.f, 0.f};
            acc[i][j] = z;
        }

    uint4 sa[4], sb[4];
    float4 sa32[8];

    auto loads = [&](int kt) {
        if constexpr (AF32) {
            const float* ap = Af + (size_t)(m0 + r) * KD + kt * 64 + cb * 8;
            #pragma unroll
            for (int c = 0; c < 4; ++c) {
                sa32[2 * c]     = ((const float4*)ap)[2 * c];
                sa32[2 * c + 1] = ((const float4*)ap)[2 * c + 1];
            }
        } else {
            const __half* ap = Ah + (size_t)(m0 + r) * KD + kt * 64 + cb * 8;
            #pragma unroll
            for (int c = 0; c < 4; ++c) sa[c] = ((const uint4*)ap)[c];
        }
        const __half* bp = Bh + (size_t)(n0 + r) * KD + kt * 64 + cb * 8;
        #pragma unroll
        for (int c = 0; c < 4; ++c) sb[c] = ((const uint4*)bp)[c];
    };

    auto dswrite = [&]() {
        #pragma unroll
        for (int c = 0; c < 4; ++c) {
            uint4 va;
            if constexpr (AF32) va = cvt8(sa32[2 * c], sa32[2 * c + 1]);
            else                va = sa[c];
            *(uint4*)((char*)As + sw(r, cb + c)) = va;
            *(uint4*)((char*)Bs + sw(r, cb + c)) = sb[c];
        }
    };

    auto compute = [&]() {
        #pragma unroll
        for (int kc = 0; kc < 2; ++kc) {
            f16x8 af[4], bf[4];
            #pragma unroll
            for (int mi = 0; mi < 4; ++mi)
                af[mi] = *(const f16x8*)((const char*)As + sw(wm * 64 + mi * 16 + l15, kc * 4 + lq));
            #pragma unroll
            for (int ni = 0; ni < 4; ++ni)
                bf[ni] = *(const f16x8*)((const char*)Bs + sw(wn * 64 + ni * 16 + l15, kc * 4 + lq));
            #pragma unroll
            for (int mi = 0; mi < 4; ++mi)
                #pragma unroll
                for (int ni = 0; ni < 4; ++ni)
                    acc[mi][ni] = __builtin_amdgcn_mfma_f32_16x16x32_f16(af[mi], bf[ni], acc[mi][ni], 0, 0, 0);
        }
    };

    loads(0);
    for (int kt = 0; kt < KT; ++kt) {
        __syncthreads();                 // previous compute done with LDS
        dswrite();
        __syncthreads();
        if (kt + 1 < KT) loads(kt + 1);  // hide HBM latency under compute (T14)
        compute();
    }

    // epilogue: D[row=(lq*4+r)][col=l15] per tile; pair cols via shfl -> dword store
    #pragma unroll
    for (int ni = 0; ni < 4; ++ni) {
        const int col = n0 + wn * 64 + ni * 16 + l15;
        const float bv = bias[col];
        #pragma unroll
        for (int mi = 0; mi < 4; ++mi) {
            f32x4 d = acc[mi][ni];
            #pragma unroll
            for (int rr = 0; rr < 4; ++rr) {
                float v = d[rr] + bv;
                if (RELU) v = fmaxf(v, 0.0f);
                uint32_t u = (uint32_t)__half_as_ushort(__float2half(v));
                uint32_t nb = (uint32_t)__shfl_xor((int)u, 1);
                if (!(lane & 1)) {
                    const int row = m0 + wm * 64 + mi * 16 + lq * 4 + rr;
                    C[(size_t)row * (N >> 1) + (col >> 1)] = u | (nb << 16);
                }
            }
        }
    }
}

// ---------------------------------------------------------------------------
// Weight pack kernels (fp32 -> fp16)
// ---------------------------------------------------------------------------
__global__ void pack_half(const float* __restrict__ in, uint32_t* __restrict__ out, int n2)
{
    int i = blockIdx.x * 256 + threadIdx.x;
    if (i < n2) {
        float2 f = ((const float2*)in)[i];
        out[i] = h2u(__floats2half2_rn(f.x, f.y));
    }
}

// W_hh packed in gru_seg per-thread order: out[(t*6+j)*32+kk] = half2 of
// Whh[r1+j*128][q*64+2kk .. +1], t = q*128+r1.
__global__ void pack_whh(const float* __restrict__ Whh, uint32_t* __restrict__ out)
{
    int p = blockIdx.x * 256 + threadIdx.x;
    if (p >= 512 * 192) return;
    int t = p / 192, rem = p - t * 192;
    int j = rem >> 5, kk = rem & 31;
    int q = t >> 7, r1 = t & 127;
    int row = r1 + j * 128, col = q * 64 + kk * 2;
    out[p] = h2u(__floats2half2_rn(Whh[row * 256 + col], Whh[row * 256 + col + 1]));
}

// ---------------------------------------------------------------------------
// Segment builder: every m==0 step resets h, so the scan splits into
// independent segments. One block per batch: flag, prefix-scan, scatter.
// ---------------------------------------------------------------------------
__global__ __launch_bounds__(512)
void seg_build(const int* __restrict__ masks, int* __restrict__ seg_start,
               int* __restrict__ seg_cnt)
{
    __shared__ int sc[512];
    const int b = blockIdx.x, s = threadIdx.x;
    const int is = (s == 0) || (masks[b * (T_ - 1) + s - 1] == 0);
    sc[s] = is;
    __syncthreads();
    #pragma unroll
    for (int off = 1; off < 512; off <<= 1) {
        int v = (s >= off) ? sc[s - off] : 0;
        __syncthreads();
        sc[s] += v;
        __syncthreads();
    }
    if (is) seg_start[b * 512 + sc[s] - 1] = s;
    if (s == 511) seg_cnt[b] = sc[s];
}

// ---------------------------------------------------------------------------
// Segment-parallel GRU. 256 blocks (1/CU), 512 threads, W_hh fp16 in regs
// (192 half2/thread -- needs the 256-reg/lane budget of (512,2); (512,4)
// spilled to scratch in round 2: FETCH 1.35GB, 4x slowdown).
// ---------------------------------------------------------------------------
__global__ __launch_bounds__(512, 2)
void gru_seg(const __half2* __restrict__ gx,     // (B*T) x 384 h2, batch-major
             const uint32_t* __restrict__ WhhP,  // packed per-thread fp16
             const float* __restrict__ bhh,      // 768
             const float* __restrict__ h0,       // B x 256
             const int* __restrict__ seg_start,
             const int* __restrict__ seg_cnt,
             uint32_t* __restrict__ hs2)         // (B*T) x 128 h2
{
    __shared__ __align__(16) uint32_t h2buf[128];
    __shared__ float part[3072];
    __shared__ int scnt[B_];
    const int tid = threadIdx.x;
    const int q = tid >> 7;        // k-quarter 0..3
    const int r1 = tid & 127;

    // weight registers: 6 outputs x 32 half2 (64 k each), 48 contiguous uint4
    __half2 w[6][32];
    {
        const uint4* wv4 = (const uint4*)(WhhP + (size_t)tid * 192);
        #pragma unroll
        for (int v = 0; v < 48; ++v) {
            uint4 x = wv4[v];
            const int j = v >> 3, k0 = (v & 7) * 4;
            w[j][k0 + 0] = u2h(x.x); w[j][k0 + 1] = u2h(x.y);
            w[j][k0 + 2] = u2h(x.z); w[j][k0 + 3] = u2h(x.w);
        }
    }
    float bh_r = 0.f, bh_z = 0.f, bh_n = 0.f;
    if (tid < 256) {
        bh_r = bhh[tid];
        bh_z = bhh[tid + 256];
        bh_n = bhh[tid + 512];
    }
    if (tid < B_) scnt[tid] = seg_cnt[tid];
    __syncthreads();

    const uint4* h2v = (const uint4*)h2buf;
    const __half2 hz = __float2half2_rn(0.0f);
    float hreg = 0.f;

    for (int slot = blockIdx.x; slot < B_ * 512; slot += gridDim.x) {
        const int b = slot >> 9, i0 = slot & 511;
        const int cnt = scnt[b];
        if (i0 >= cnt) continue;
        const int start = seg_start[slot];
        const int nxt = (i0 + 1 < cnt) ? seg_start[slot + 1] : T_;
        const int len = nxt - start;

        if (start == 0) {   // batch-initial segment: h from h0, full dot at step 0
            if (tid < 256) hreg = h0[b * 256 + tid];
            if (tid < 128) {
                float2 f = ((const float2*)(h0 + b * 256))[tid];
                h2buf[tid] = h2u(__floats2half2_rn(f.x, f.y));
            }
            __syncthreads();
        }
        float gxr = 0.f, gxz = 0.f, gxn = 0.f;
        if (tid < 256) {
            const __half* grow = (const __half*)(gx + (size_t)(b * T_ + start) * 384);
            gxr = __half2float(grow[tid]);
            gxz = __half2float(grow[tid + 256]);
            gxn = __half2float(grow[tid + 512]);
        }
        for (int i = 0; i < len; ++i) {
            const bool md = (i > 0) || (start == 0);   // uniform across block
            if (md) {
                __half2 acc0 = hz, acc1 = hz, acc2 = hz, acc3 = hz, acc4 = hz, acc5 = hz;
                #pragma unroll
                for (int kb = 0; kb < 8; ++kb) {
                    uint4 hv = h2v[q * 8 + kb];
                    __half2 e0 = u2h(hv.x), e1 = u2h(hv.y), e2 = u2h(hv.z), e3 = u2h(hv.w);
                    acc0 = __hfma2(w[0][kb*4+0], e0, acc0); acc0 = __hfma2(w[0][kb*4+1], e1, acc0);
                    acc0 = __hfma2(w[0][kb*4+2], e2, acc0); acc0 = __hfma2(w[0][kb*4+3], e3, acc0);
                    acc1 = __hfma2(w[1][kb*4+0], e0, acc1); acc1 = __hfma2(w[1][kb*4+1], e1, acc1);
                    acc1 = __hfma2(w[1][kb*4+2], e2, acc1); acc1 = __hfma2(w[1][kb*4+3], e3, acc1);
                    acc2 = __hfma2(w[2][kb*4+0], e0, acc2); acc2 = __hfma2(w[2][kb*4+1], e1, acc2);
                    acc2 = __hfma2(w[2][kb*4+2], e2, acc2); acc2 = __hfma2(w[2][kb*4+3], e3, acc2);
                    acc3 = __hfma2(w[3][kb*4+0], e0, acc3); acc3 = __hfma2(w[3][kb*4+1], e1, acc3);
                    acc3 = __hfma2(w[3][kb*4+2], e2, acc3); acc3 = __hfma2(w[3][kb*4+3], e3, acc3);
                    acc4 = __hfma2(w[4][kb*4+0], e0, acc4); acc4 = __hfma2(w[4][kb*4+1], e1, acc4);
                    acc4 = __hfma2(w[4][kb*4+2], e2, acc4); acc4 = __hfma2(w[4][kb*4+3], e3, acc4);
                    acc5 = __hfma2(w[5][kb*4+0], e0, acc5); acc5 = __hfma2(w[5][kb*4+1], e1, acc5);
                    acc5 = __hfma2(w[5][kb*4+2], e2, acc5); acc5 = __hfma2(w[5][kb*4+3], e3, acc5);
                }
                part[r1 + 0 * 128 + q * 768] = __low2float(acc0) + __high2float(acc0);
                part[r1 + 1 * 128 + q * 768] = __low2float(acc1) + __high2float(acc1);
                part[r1 + 2 * 128 + q * 768] = __low2float(acc2) + __high2float(acc2);
                part[r1 + 3 * 128 + q * 768] = __low2float(acc3) + __high2float(acc3);
                part[r1 + 4 * 128 + q * 768] = __low2float(acc4) + __high2float(acc4);
                part[r1 + 5 * 128 + q * 768] = __low2float(acc5) + __high2float(acc5);
            }
            // rotate: issue next step's gx load before the barrier+gates
            float nr = 0.f, nz = 0.f, nn = 0.f;
            if (tid < 256 && i + 1 < len) {
                const __half* grow = (const __half*)(gx + (size_t)(b * T_ + start + i + 1) * 384);
                nr = __half2float(grow[tid]);
                nz = __half2float(grow[tid + 256]);
                nn = __half2float(grow[tid + 512]);
            }
            if (md) __syncthreads();
            if (tid < 256) {
                float ghr = bh_r, ghz = bh_z, ghn = bh_n;
                if (md) {
                    ghr += part[tid]       + part[tid + 768]       + part[tid + 1536]       + part[tid + 2304];
                    ghz += part[tid + 256] + part[tid + 256 + 768] + part[tid + 256 + 1536] + part[tid + 256 + 2304];
                    ghn += part[tid + 512] + part[tid + 512 + 768] + part[tid + 512 + 1536] + part[tid + 512 + 2304];
                }
                const float hp = md ? hreg : 0.0f;
                const float rg = 1.0f / (1.0f + exp2f(-(gxr + ghr) * 1.44269504f));
                const float zg = 1.0f / (1.0f + exp2f(-(gxz + ghz) * 1.44269504f));
                const float nin = gxn + rg * ghn;
                const float e2x = exp2f(nin * 2.885390082f);
                const float ng = 1.0f - 2.0f / (e2x + 1.0f);      // tanh(nin)
                const float hnew = (1.0f - zg) * ng + zg * hp;
                hreg = hnew;
                const float other = __shfl_xor(hnew, 1);
                if ((tid & 1) == 0) {
                    const uint32_t hp2 = h2u(__floats2half2_rn(hnew, other));
                    h2buf[tid >> 1] = hp2;
                    hs2[(size_t)(b * T_ + start + i) * 128 + (tid >> 1)] = hp2;
                }
            }
            gxr = nr; gxz = nz; gxn = nn;
            __syncthreads();
        }
    }
}

// ---------------------------------------------------------------------------
// Heads: one wave per output row (hs fp16). 11 dots of 256, butterfly reduce,
// stable log_softmax, entropy, action gather.
// ---------------------------------------------------------------------------
__global__ __launch_bounds__(256)
void heads_kernel(const uint32_t* __restrict__ hs2, const float* __restrict__ Wa,
                  const float* __restrict__ ba, const float* __restrict__ Wc,
                  const float* __restrict__ bc, const int* __restrict__ action,
                  float* __restrict__ out)
{
    const int wid = threadIdx.x >> 6, lane = threadIdx.x & 63;
    const int row = blockIdx.x * 4 + wid;
    const uint2 hv2 = ((const uint2*)(hs2 + (size_t)row * 128))[lane];
    const __half2 ha = u2h(hv2.x), hb = u2h(hv2.y);
    const float h0f = __low2float(ha), h1f = __high2float(ha);
    const float h2f = __low2float(hb), h3f = __high2float(hb);
    float sums[11];
    #pragma unroll
    for (int n = 0; n < 11; ++n) {
        const float* wrow = (n < 10) ? (Wa + n * 256) : Wc;
        const float4 wv = ((const float4*)wrow)[lane];
        sums[n] = h0f * wv.x + h1f * wv.y + h2f * wv.z + h3f * wv.w;
    }
    #pragma unroll
    for (int n = 0; n < 11; ++n) {
        float v = sums[n];
        #pragma unroll
        for (int off = 32; off; off >>= 1) v += __shfl_xor(v, off);
        sums[n] = v;
    }
    float logits[10];
    #pragma unroll
    for (int n = 0; n < 10; ++n) logits[n] = sums[n] + ba[n];
    const float value = sums[10] + bc[0];
    float mx = logits[0];
    #pragma unroll
    for (int n = 1; n < 10; ++n) mx = fmaxf(mx, logits[n]);
    float ssum = 0.f, sdot = 0.f;
    #pragma unroll
    for (int n = 0; n < 10; ++n) {
        float d = logits[n] - mx;
        float e = exp2f(d * 1.44269504f);
        ssum += e; sdot += e * d;
    }
    const float lns = logf(ssum);
    const float lse = mx + lns;
    const float entropy = lns - sdot / ssum;
    const int a = action[row];
    float la = 0.f;
    #pragma unroll
    for (int n = 0; n < 10; ++n) la = (n == a) ? logits[n] : la;
    if (lane == 0) {
        out[row] = value;
        out[BT_ + row] = la - lse;
        out[2 * BT_ + row] = entropy;
    }
}

// ---------------------------------------------------------------------------
extern "C" void kernel_launch(void* const* d_in, const int* in_sizes, int n_in,
                              void* d_out, int out_size, void* d_ws, size_t ws_size,
                              hipStream_t stream)
{
    const float* obs    = (const float*)d_in[0];
    const int*   action = (const int*)d_in[1];
    const int*   masks  = (const int*)d_in[2];
    const float* h0     = (const float*)d_in[3];
    const float* W1     = (const float*)d_in[4];
    const float* b1     = (const float*)d_in[5];
    const float* Wih    = (const float*)d_in[6];
    const float* Whh    = (const float*)d_in[7];
    const float* bih    = (const float*)d_in[8];
    const float* bhh    = (const float*)d_in[9];
    const float* Wa     = (const float*)d_in[10];
    const float* ba     = (const float*)d_in[11];
    const float* Wc     = (const float*)d_in[12];
    const float* bc     = (const float*)d_in[13];
    float* out = (float*)d_out;

    char* p = (char*)d_ws;
    __half*   feat = (__half*)p;    p += (size_t)BT_ * FEAT_ * 2;   // 33.6 MB
    __half*   gx   = (__half*)p;    p += (size_t)BT_ * G_ * 2;      // 50.3 MB
    uint32_t* hs2  = (uint32_t*)p;  p += (size_t)BT_ * H_ * 2;      // 16.8 MB
    __half*   W1h  = (__half*)p;    p += FEAT_ * OBS_ * 2;          // 131 KB
    __half*   Wihh = (__half*)p;    p += G_ * FEAT_ * 2;            // 786 KB
    uint32_t* WhhP = (uint32_t*)p;  p += 512 * 192 * 4;             // 393 KB
    int*      sstrt= (int*)p;       p += B_ * 512 * 4;              // 131 KB
    int*      scnt = (int*)p;       p += 256;

    // weight packs + segment decomposition (all independent, tiny)
    pack_half<<<(FEAT_ * OBS_ / 2 + 255) / 256, 256, 0, stream>>>(W1, (uint32_t*)W1h, FEAT_ * OBS_ / 2);
    pack_half<<<(G_ * FEAT_ / 2 + 255) / 256, 256, 0, stream>>>(Wih, (uint32_t*)Wihh, G_ * FEAT_ / 2);
    pack_whh<<<384, 256, 0, stream>>>(Whh, WhhP);
    seg_build<<<B_, 512, 0, stream>>>(masks, sstrt, scnt);
    // feat = relu(obs @ W1^T + b1)
    mfma_gemm<OBS_, true, true><<<dim3(256, 4), 256, 0, stream>>>(obs, nullptr, W1h, b1, (uint32_t*)feat, FEAT_);
    // gx = feat @ W_ih^T + b_ih   (batch-major rows)
    mfma_gemm<FEAT_, false, false><<<dim3(256, 6), 256, 0, stream>>>(nullptr, feat, Wihh, bih, (uint32_t*)gx, G_);
    // segment-parallel recurrence
    gru_seg<<<256, 512, 0, stream>>>((const __half2*)gx, WhhP, bhh, h0, sstrt, scnt, hs2);
    // heads
    heads_kernel<<<8192, 256, 0, stream>>>(hs2, Wa, ba, Wc, bc, action, out);
}

// Round 4
// 302.858 us; speedup vs baseline: 8.5773x; 1.3495x over previous
//
#include <hip/hip_runtime.h>
#include <hip/hip_fp16.h>
#include <stdint.h>

#define B_    64
#define T_    512
#define OBS_  128
#define FEAT_ 512
#define H_    256
#define G_    768
#define BT_   32768
#define NA_   10

typedef _Float16 f16x8 __attribute__((ext_vector_type(8)));
typedef float    f32x4 __attribute__((ext_vector_type(4)));

__device__ __forceinline__ uint32_t h2u(__half2 h){ union{ __half2 h; uint32_t u; } c; c.h = h; return c.u; }
__device__ __forceinline__ __half2 u2h(uint32_t u){ union{ uint32_t u; __half2 h; } c; c.u = u; return c.h; }

// swizzled LDS byte offset: tile [128 rows][8 chunks of 16B], chunk ^= row&7
__device__ __forceinline__ int sw(int r, int c) { return r * 128 + ((c ^ (r & 7)) << 4); }

__device__ __forceinline__ uint4 cvt8(float4 a, float4 b) {
    uint4 u;
    u.x = h2u(__floats2half2_rn(a.x, a.y));
    u.y = h2u(__floats2half2_rn(a.z, a.w));
    u.z = h2u(__floats2half2_rn(b.x, b.y));
    u.w = h2u(__floats2half2_rn(b.z, b.w));
    return u;
}

// ---------------------------------------------------------------------------
// MFMA GEMM: C[M x N](fp16) = act( A[M x K] @ W[N x K]^T + bias )
// 128x128 tile, BK=64, 4 waves (2x2), each wave 4x4 frags of 16x16x32_f16.
// (unchanged from round 3 -- passed)
// ---------------------------------------------------------------------------
template<int KD, bool AF32, bool RELU>
__global__ __launch_bounds__(256, 2)
void mfma_gemm(const float* __restrict__ Af, const __half* __restrict__ Ah,
               const __half* __restrict__ Bh, const float* __restrict__ bias,
               uint32_t* __restrict__ C, int N)
{
    __shared__ __align__(16) __half As[128 * 64];
    __shared__ __align__(16) __half Bs[128 * 64];
    const int m0 = blockIdx.x * 128, n0 = blockIdx.y * 128;
    const int tid = threadIdx.x;
    const int r = tid >> 1, cb = (tid & 1) * 4;
    const int lane = tid & 63, w = tid >> 6;
    const int wm = w >> 1, wn = w & 1;
    const int l15 = lane & 15, lq = lane >> 4;
    constexpr int KT = KD / 64;

    f32x4 acc[4][4];
    #pragma unroll
    for (int i = 0; i < 4; ++i)
        #pragma unroll
        for (int j = 0; j < 4; ++j) {
            f32x4 z = {0.f, 0.f, 0.f, 0.f};
            acc[i][j] = z;
        }

    uint4 sa[4], sb[4];
    float4 sa32[8];

    auto loads = [&](int kt) {
        if constexpr (AF32) {
            const float* ap = Af + (size_t)(m0 + r) * KD + kt * 64 + cb * 8;
            #pragma unroll
            for (int c = 0; c < 4; ++c) {
                sa32[2 * c]     = ((const float4*)ap)[2 * c];
                sa32[2 * c + 1] = ((const float4*)ap)[2 * c + 1];
            }
        } else {
            const __half* ap = Ah + (size_t)(m0 + r) * KD + kt * 64 + cb * 8;
            #pragma unroll
            for (int c = 0; c < 4; ++c) sa[c] = ((const uint4*)ap)[c];
        }
        const __half* bp = Bh + (size_t)(n0 + r) * KD + kt * 64 + cb * 8;
        #pragma unroll
        for (int c = 0; c < 4; ++c) sb[c] = ((const uint4*)bp)[c];
    };

    auto dswrite = [&]() {
        #pragma unroll
        for (int c = 0; c < 4; ++c) {
            uint4 va;
            if constexpr (AF32) va = cvt8(sa32[2 * c], sa32[2 * c + 1]);
            else                va = sa[c];
            *(uint4*)((char*)As + sw(r, cb + c)) = va;
            *(uint4*)((char*)Bs + sw(r, cb + c)) = sb[c];
        }
    };

    auto compute = [&]() {
        #pragma unroll
        for (int kc = 0; kc < 2; ++kc) {
            f16x8 af[4], bf[4];
            #pragma unroll
            for (int mi = 0; mi < 4; ++mi)
                af[mi] = *(const f16x8*)((const char*)As + sw(wm * 64 + mi * 16 + l15, kc * 4 + lq));
            #pragma unroll
            for (int ni = 0; ni < 4; ++ni)
                bf[ni] = *(const f16x8*)((const char*)Bs + sw(wn * 64 + ni * 16 + l15, kc * 4 + lq));
            #pragma unroll
            for (int mi = 0; mi < 4; ++mi)
                #pragma unroll
                for (int ni = 0; ni < 4; ++ni)
                    acc[mi][ni] = __builtin_amdgcn_mfma_f32_16x16x32_f16(af[mi], bf[ni], acc[mi][ni], 0, 0, 0);
        }
    };

    loads(0);
    for (int kt = 0; kt < KT; ++kt) {
        __syncthreads();
        dswrite();
        __syncthreads();
        if (kt + 1 < KT) loads(kt + 1);
        compute();
    }

    #pragma unroll
    for (int ni = 0; ni < 4; ++ni) {
        const int col = n0 + wn * 64 + ni * 16 + l15;
        const float bv = bias[col];
        #pragma unroll
        for (int mi = 0; mi < 4; ++mi) {
            f32x4 d = acc[mi][ni];
            #pragma unroll
            for (int rr = 0; rr < 4; ++rr) {
                float v = d[rr] + bv;
                if (RELU) v = fmaxf(v, 0.0f);
                uint32_t u = (uint32_t)__half_as_ushort(__float2half(v));
                uint32_t nb = (uint32_t)__shfl_xor((int)u, 1);
                if (!(lane & 1)) {
                    const int row = m0 + wm * 64 + mi * 16 + lq * 4 + rr;
                    C[(size_t)row * (N >> 1) + (col >> 1)] = u | (nb << 16);
                }
            }
        }
    }
}

// ---------------------------------------------------------------------------
// Weight packs (fp32 -> fp16); pack_whh also zeroes the queue control ints
// (runs before seg_build / gru_seg on the same stream -> re-zeroed every call)
// ---------------------------------------------------------------------------
__global__ void pack_half(const float* __restrict__ in, uint32_t* __restrict__ out, int n2)
{
    int i = blockIdx.x * 256 + threadIdx.x;
    if (i < n2) {
        float2 f = ((const float2*)in)[i];
        out[i] = h2u(__floats2half2_rn(f.x, f.y));
    }
}

__global__ void pack_whh(const float* __restrict__ Whh, uint32_t* __restrict__ out,
                         int* __restrict__ qctl)
{
    if (blockIdx.x == 0 && threadIdx.x == 0) { qctl[0] = 0; qctl[1] = 0; }
    int p = blockIdx.x * 256 + threadIdx.x;
    if (p >= 512 * 192) return;
    int t = p / 192, rem = p - t * 192;
    int j = rem >> 5, kk = rem & 31;
    int q = t >> 7, r1 = t & 127;
    int row = r1 + j * 128, col = q * 64 + kk * 2;
    out[p] = h2u(__floats2half2_rn(Whh[row * 256 + col], Whh[row * 256 + col + 1]));
}

// ---------------------------------------------------------------------------
// Segment builder -> compacted work queue. Entry = (b<<19)|(start<<10)|len.
// Only segments needing the scan: start==0 (h0 seed) or len>=2.
// len-1 non-initial segments are fully handled by h0pre.
// ---------------------------------------------------------------------------
__global__ __launch_bounds__(512)
void seg_build(const int* __restrict__ masks, int* __restrict__ queue,
               int* __restrict__ qtail)
{
    __shared__ int sc[512];
    __shared__ int starts[512];
    __shared__ int cshr[2];
    const int b = blockIdx.x, s = threadIdx.x;
    const int is = (s == 0) || (masks[b * (T_ - 1) + s - 1] == 0);
    sc[s] = is;
    __syncthreads();
    #pragma unroll
    for (int off = 1; off < 512; off <<= 1) {
        int v = (s >= off) ? sc[s - off] : 0;
        __syncthreads();
        sc[s] += v;
        __syncthreads();
    }
    if (is) starts[sc[s] - 1] = s;
    if (s == 511) cshr[0] = sc[511];
    __syncthreads();
    const int cnt = cshr[0];
    int valid = 0, st = 0, ln = 0;
    if (s < cnt) {
        st = starts[s];
        const int nxt = (s + 1 < cnt) ? starts[s + 1] : T_;
        ln = nxt - st;
        valid = (st == 0 || ln >= 2) ? 1 : 0;
    }
    sc[s] = valid;
    __syncthreads();
    #pragma unroll
    for (int off = 1; off < 512; off <<= 1) {
        int v = (s >= off) ? sc[s - off] : 0;
        __syncthreads();
        sc[s] += v;
        __syncthreads();
    }
    if (s == 511) cshr[1] = atomicAdd(qtail, sc[511]);
    __syncthreads();
    if (valid) queue[cshr[1] + sc[s] - 1] = (b << 19) | (st << 10) | ln;
}

// ---------------------------------------------------------------------------
// Pre-pass: every step t>=1 with mask==0 has h_prev==0 -> gh = b_hh only.
// Pure elementwise; covers ~half of all steps incl. all len-1 segments.
// ---------------------------------------------------------------------------
__global__ __launch_bounds__(256)
void h0pre(const __half* __restrict__ gx, const float* __restrict__ bhh,
           const int* __restrict__ masks, uint32_t* __restrict__ hs2)
{
    const int row = blockIdx.x;                 // 0 .. B*(T-1)-1
    if (masks[row] != 0) return;
    const int b = row / (T_ - 1), t = 1 + row - b * (T_ - 1);
    const int e = threadIdx.x;
    const __half* grow = gx + (size_t)(b * T_ + t) * 768;
    const float gxr = __half2float(grow[e]);
    const float gxz = __half2float(grow[e + 256]);
    const float gxn = __half2float(grow[e + 512]);
    const float rg = 1.f / (1.f + exp2f(-(gxr + bhh[e]) * 1.44269504f));
    const float zg = 1.f / (1.f + exp2f(-(gxz + bhh[e + 256]) * 1.44269504f));
    const float nin = gxn + rg * bhh[e + 512];
    const float e2x = exp2f(nin * 2.885390082f);
    const float ng = 1.f - 2.f / (e2x + 1.f);
    const float hnew = (1.f - zg) * ng;         // h_prev = 0
    const float other = __shfl_xor(hnew, 1);
    if (!(e & 1)) hs2[(size_t)(b * T_ + t) * 128 + (e >> 1)] = h2u(__floats2half2_rn(hnew, other));
}

// ---------------------------------------------------------------------------
// Segment-parallel GRU, 2-segment pipelined. 256 blocks (1/CU), 512 threads.
// W_hh fp16 in regs (needs the 256-reg budget of (512,2); (512,4) spilled in r2).
// Per iteration: dot(D) on all 512 threads || gates(G) on threads<256, ONE
// barrier. Segments pulled from a global work queue (atomic head).
// ---------------------------------------------------------------------------
__global__ __launch_bounds__(512, 2)
void gru_seg(const __half* __restrict__ gx,      // (B*T) x 768 halves
             const uint32_t* __restrict__ WhhP,  // packed per-thread fp16
             const float* __restrict__ bhh,
             const float* __restrict__ h0,
             const int* __restrict__ queue,
             const int* __restrict__ qtail,
             int* __restrict__ qhead,
             uint32_t* __restrict__ hs2)         // (B*T) x 128 h2
{
    __shared__ __align__(16) uint32_t h2b0[128], h2b1[128];
    __shared__ float part0[3072], part1[3072];
    __shared__ int news2[2];
    __shared__ int news;
    const int tid = threadIdx.x;
    const int q = tid >> 7, r1 = tid & 127;

    __half2 w[6][32];
    {
        const uint4* wv4 = (const uint4*)(WhhP + (size_t)tid * 192);
        #pragma unroll
        for (int v = 0; v < 48; ++v) {
            uint4 x = wv4[v];
            const int j = v >> 3, k0 = (v & 7) * 4;
            w[j][k0 + 0] = u2h(x.x); w[j][k0 + 1] = u2h(x.y);
            w[j][k0 + 2] = u2h(x.z); w[j][k0 + 3] = u2h(x.w);
        }
    }
    float bh_r = 0.f, bh_z = 0.f, bh_n = 0.f;
    if (tid < 256) {
        bh_r = bhh[tid];
        bh_z = bhh[tid + 256];
        bh_n = bhh[tid + 512];
    }
    const int NQ = *qtail;
    const __half2 hz = __float2half2_rn(0.0f);

    // pipe state: uniform scalars (b,t,tend,active,pend) + per-thread floats
    int  bA = 0, tA = 0, eA = 0, bB = 0, tB = 0, eB = 0;
    bool aA = false, pA = false, aB = false, pB = false;
    float hrA = 0.f, grA = 0.f, gzA = 0.f, gnA = 0.f;
    float hrB = 0.f, grB = 0.f, gzB = 0.f, gnB = 0.f;

    auto refillNow = [&](int s, bool& aX, int& bX, int& tX, int& eX,
                         float& hrX, uint32_t* h2bX) {
        if (s < 0) { aX = false; return; }
        aX = true;
        const int ln = s & 1023, st = (s >> 10) & 511;
        bX = s >> 19;
        if (st == 0) {
            tX = 0; eX = ln;
            if (tid < 256) hrX = h0[bX * 256 + tid];
            if (tid < 128) {
                float2 f = ((const float2*)(h0 + bX * 256))[tid];
                h2bX[tid] = h2u(__floats2half2_rn(f.x, f.y));
            }
        } else {
            tX = st + 1; eX = st + ln;
            if (tid < 256) hrX = __half2float(((const __half*)(hs2 + (size_t)(bX * T_ + st) * 128))[tid]);
            if (tid < 128) h2bX[tid] = hs2[(size_t)(bX * T_ + st) * 128 + tid];
        }
    };

    // one pipeline iteration: D dots, G gates. Exactly one __syncthreads at
    // the end (plus one extra when G finishes a segment and pops a new one).
    auto iteration = [&](bool& aD, bool& pD, int& bD, int& tD, int& eD,
                         float& hrD, float& grD, float& gzD, float& gnD,
                         const uint32_t* h2bD, float* partD,
                         bool& aG, bool& pG, int& bG, int& tG, int& eG,
                         float& hrG, float& grG, float& gzG, float& gnG,
                         uint32_t* h2bG, float* partG) {
        const bool ending = pG && (tG + 1 == eG);     // uniform
        int nb = 0, nt = 0, ne = 0; bool nact = false;
        float thr = 0.f; uint32_t th2 = 0;
        if (ending) {   // pop + ISSUE next-segment state loads early (hide under dot)
            if (tid == 0) { int p = atomicAdd(qhead, 1); news = (p < NQ) ? queue[p] : -1; }
            __syncthreads();
            const int s = news;
            if (s >= 0) {
                nact = true;
                const int ln = s & 1023, st = (s >> 10) & 511;
                nb = s >> 19;
                if (st == 0) {
                    nt = 0; ne = ln;
                    if (tid < 256) thr = h0[nb * 256 + tid];
                    if (tid < 128) {
                        float2 f = ((const float2*)(h0 + nb * 256))[tid];
                        th2 = h2u(__floats2half2_rn(f.x, f.y));
                    }
                } else {
                    nt = st + 1; ne = st + ln;
                    if (tid < 256) thr = __half2float(((const __half*)(hs2 + (size_t)(nb * T_ + st) * 128))[tid]);
                    if (tid < 128) th2 = hs2[(size_t)(nb * T_ + st) * 128 + tid];
                }
            }
        }
        // ---- DOT for D ----
        if (aD && !pD) {
            const uint4* h2v = (const uint4*)h2bD;
            __half2 acc0 = hz, acc1 = hz, acc2 = hz, acc3 = hz, acc4 = hz, acc5 = hz;
            #pragma unroll
            for (int kb = 0; kb < 8; ++kb) {
                uint4 hv = h2v[q * 8 + kb];
                __half2 x0 = u2h(hv.x), x1 = u2h(hv.y), x2 = u2h(hv.z), x3 = u2h(hv.w);
                acc0 = __hfma2(w[0][kb*4+0], x0, acc0); acc0 = __hfma2(w[0][kb*4+1], x1, acc0);
                acc0 = __hfma2(w[0][kb*4+2], x2, acc0); acc0 = __hfma2(w[0][kb*4+3], x3, acc0);
                acc1 = __hfma2(w[1][kb*4+0], x0, acc1); acc1 = __hfma2(w[1][kb*4+1], x1, acc1);
                acc1 = __hfma2(w[1][kb*4+2], x2, acc1); acc1 = __hfma2(w[1][kb*4+3], x3, acc1);
                acc2 = __hfma2(w[2][kb*4+0], x0, acc2); acc2 = __hfma2(w[2][kb*4+1], x1, acc2);
                acc2 = __hfma2(w[2][kb*4+2], x2, acc2); acc2 = __hfma2(w[2][kb*4+3], x3, acc2);
                acc3 = __hfma2(w[3][kb*4+0], x0, acc3); acc3 = __hfma2(w[3][kb*4+1], x1, acc3);
                acc3 = __hfma2(w[3][kb*4+2], x2, acc3); acc3 = __hfma2(w[3][kb*4+3], x3, acc3);
                acc4 = __hfma2(w[4][kb*4+0], x0, acc4); acc4 = __hfma2(w[4][kb*4+1], x1, acc4);
                acc4 = __hfma2(w[4][kb*4+2], x2, acc4); acc4 = __hfma2(w[4][kb*4+3], x3, acc4);
                acc5 = __hfma2(w[5][kb*4+0], x0, acc5); acc5 = __hfma2(w[5][kb*4+1], x1, acc5);
                acc5 = __hfma2(w[5][kb*4+2], x2, acc5); acc5 = __hfma2(w[5][kb*4+3], x3, acc5);
            }
            partD[r1 + 0 * 128 + q * 768] = __low2float(acc0) + __high2float(acc0);
            partD[r1 + 1 * 128 + q * 768] = __low2float(acc1) + __high2float(acc1);
            partD[r1 + 2 * 128 + q * 768] = __low2float(acc2) + __high2float(acc2);
            partD[r1 + 3 * 128 + q * 768] = __low2float(acc3) + __high2float(acc3);
            partD[r1 + 4 * 128 + q * 768] = __low2float(acc4) + __high2float(acc4);
            partD[r1 + 5 * 128 + q * 768] = __low2float(acc5) + __high2float(acc5);
        }
        // ---- GATES for G (partials written when G was dotting, last iter) ----
        if (pG && tid < 256) {
            float ghr = bh_r + partG[tid]       + partG[tid + 768]       + partG[tid + 1536]       + partG[tid + 2304];
            float ghz = bh_z + partG[tid + 256] + partG[tid + 256 + 768] + partG[tid + 256 + 1536] + partG[tid + 256 + 2304];
            float ghn = bh_n + partG[tid + 512] + partG[tid + 512 + 768] + partG[tid + 512 + 1536] + partG[tid + 512 + 2304];
            const float rg = 1.0f / (1.0f + exp2f(-(grG + ghr) * 1.44269504f));
            const float zg = 1.0f / (1.0f + exp2f(-(gzG + ghz) * 1.44269504f));
            const float nin = gnG + rg * ghn;
            const float e2x = exp2f(nin * 2.885390082f);
            const float ng = 1.0f - 2.0f / (e2x + 1.0f);
            const float hnew = (1.0f - zg) * ng + zg * hrG;
            hrG = hnew;
            const float other = __shfl_xor(hnew, 1);
            if (!(tid & 1)) {
                const uint32_t hp2 = h2u(__floats2half2_rn(hnew, other));
                hs2[(size_t)(bG * T_ + tG) * 128 + (tid >> 1)] = hp2;
                if (!ending) h2bG[tid >> 1] = hp2;
            }
        }
        // ---- advance / commit G ----
        if (ending) {
            aG = nact; pG = false;
            if (nact) {
                bG = nb; tG = nt; eG = ne; hrG = thr;
                if (tid < 128) h2bG[tid] = th2;
            }
        } else if (pG) { tG++; pG = false; }
        // ---- prefetch gx for the step D just dotted (gated next iteration) ----
        if (aD) {
            if (tid < 256) {
                const __half* grow = gx + (size_t)(bD * T_ + tD) * 768;
                grD = __half2float(grow[tid]);
                gzD = __half2float(grow[tid + 256]);
                gnD = __half2float(grow[tid + 512]);
            }
            pD = true;
        }
        __syncthreads();
    };

    // initial fill: pop two slots
    if (tid == 0) {
        int p = atomicAdd(qhead, 2);
        news2[0] = (p < NQ) ? queue[p] : -1;
        news2[1] = (p + 1 < NQ) ? queue[p + 1] : -1;
    }
    __syncthreads();
    refillNow(news2[0], aA, bA, tA, eA, hrA, h2b0);
    refillNow(news2[1], aB, bB, tB, eB, hrB, h2b1);
    __syncthreads();

    while (aA || aB) {
        iteration(aA, pA, bA, tA, eA, hrA, grA, gzA, gnA, h2b0, part0,
                  aB, pB, bB, tB, eB, hrB, grB, gzB, gnB, h2b1, part1);
        iteration(aB, pB, bB, tB, eB, hrB, grB, gzB, gnB, h2b1, part1,
                  aA, pA, bA, tA, eA, hrA, grA, gzA, gnA, h2b0, part0);
    }
}

// ---------------------------------------------------------------------------
// Heads (unchanged): one wave per output row, hs fp16.
// ---------------------------------------------------------------------------
__global__ __launch_bounds__(256)
void heads_kernel(const uint32_t* __restrict__ hs2, const float* __restrict__ Wa,
                  const float* __restrict__ ba, const float* __restrict__ Wc,
                  const float* __restrict__ bc, const int* __restrict__ action,
                  float* __restrict__ out)
{
    const int wid = threadIdx.x >> 6, lane = threadIdx.x & 63;
    const int row = blockIdx.x * 4 + wid;
    const uint2 hv2 = ((const uint2*)(hs2 + (size_t)row * 128))[lane];
    const __half2 ha = u2h(hv2.x), hb = u2h(hv2.y);
    const float h0f = __low2float(ha), h1f = __high2float(ha);
    const float h2f = __low2float(hb), h3f = __high2float(hb);
    float sums[11];
    #pragma unroll
    for (int n = 0; n < 11; ++n) {
        const float* wrow = (n < 10) ? (Wa + n * 256) : Wc;
        const float4 wv = ((const float4*)wrow)[lane];
        sums[n] = h0f * wv.x + h1f * wv.y + h2f * wv.z + h3f * wv.w;
    }
    #pragma unroll
    for (int n = 0; n < 11; ++n) {
        float v = sums[n];
        #pragma unroll
        for (int off = 32; off; off >>= 1) v += __shfl_xor(v, off);
        sums[n] = v;
    }
    float logits[10];
    #pragma unroll
    for (int n = 0; n < 10; ++n) logits[n] = sums[n] + ba[n];
    const float value = sums[10] + bc[0];
    float mx = logits[0];
    #pragma unroll
    for (int n = 1; n < 10; ++n) mx = fmaxf(mx, logits[n]);
    float ssum = 0.f, sdot = 0.f;
    #pragma unroll
    for (int n = 0; n < 10; ++n) {
        float d = logits[n] - mx;
        float e = exp2f(d * 1.44269504f);
        ssum += e; sdot += e * d;
    }
    const float lns = logf(ssum);
    const float lse = mx + lns;
    const float entropy = lns - sdot / ssum;
    const int a = action[row];
    float la = 0.f;
    #pragma unroll
    for (int n = 0; n < 10; ++n) la = (n == a) ? logits[n] : la;
    if (lane == 0) {
        out[row] = value;
        out[BT_ + row] = la - lse;
        out[2 * BT_ + row] = entropy;
    }
}

// ---------------------------------------------------------------------------
extern "C" void kernel_launch(void* const* d_in, const int* in_sizes, int n_in,
                              void* d_out, int out_size, void* d_ws, size_t ws_size,
                              hipStream_t stream)
{
    const float* obs    = (const float*)d_in[0];
    const int*   action = (const int*)d_in[1];
    const int*   masks  = (const int*)d_in[2];
    const float* h0     = (const float*)d_in[3];
    const float* W1     = (const float*)d_in[4];
    const float* b1     = (const float*)d_in[5];
    const float* Wih    = (const float*)d_in[6];
    const float* Whh    = (const float*)d_in[7];
    const float* bih    = (const float*)d_in[8];
    const float* bhh    = (const float*)d_in[9];
    const float* Wa     = (const float*)d_in[10];
    const float* ba     = (const float*)d_in[11];
    const float* Wc     = (const float*)d_in[12];
    const float* bc     = (const float*)d_in[13];
    float* out = (float*)d_out;

    char* p = (char*)d_ws;
    __half*   feat = (__half*)p;    p += (size_t)BT_ * FEAT_ * 2;   // 33.6 MB
    __half*   gx   = (__half*)p;    p += (size_t)BT_ * G_ * 2;      // 50.3 MB
    uint32_t* hs2  = (uint32_t*)p;  p += (size_t)BT_ * H_ * 2;      // 16.8 MB
    __half*   W1h  = (__half*)p;    p += FEAT_ * OBS_ * 2;          // 131 KB
    __half*   Wihh = (__half*)p;    p += G_ * FEAT_ * 2;            // 786 KB
    uint32_t* WhhP = (uint32_t*)p;  p += 512 * 192 * 4;             // 393 KB
    int*      queue= (int*)p;       p += B_ * 512 * 4;              // 131 KB
    int*      qctl = (int*)p;       p += 256;                        // qtail, qhead

    // packs + queue-control zero (pack_whh) + segment queue build
    pack_half<<<(FEAT_ * OBS_ / 2 + 255) / 256, 256, 0, stream>>>(W1, (uint32_t*)W1h, FEAT_ * OBS_ / 2);
    pack_half<<<(G_ * FEAT_ / 2 + 255) / 256, 256, 0, stream>>>(Wih, (uint32_t*)Wihh, G_ * FEAT_ / 2);
    pack_whh<<<384, 256, 0, stream>>>(Whh, WhhP, qctl);
    seg_build<<<B_, 512, 0, stream>>>(masks, queue, &qctl[0]);
    // feat = relu(obs @ W1^T + b1)
    mfma_gemm<OBS_, true, true><<<dim3(256, 4), 256, 0, stream>>>(obs, nullptr, W1h, b1, (uint32_t*)feat, FEAT_);
    // gx = feat @ W_ih^T + b_ih   (batch-major rows)
    mfma_gemm<FEAT_, false, false><<<dim3(256, 6), 256, 0, stream>>>(nullptr, feat, Wihh, bih, (uint32_t*)gx, G_);
    // pre-pass: all h_prev==0 steps (elementwise)
    h0pre<<<B_ * (T_ - 1), 256, 0, stream>>>(gx, bhh, masks, hs2);
    // pipelined segment-parallel recurrence
    gru_seg<<<256, 512, 0, stream>>>(gx, WhhP, bhh, h0, queue, &qctl[0], &qctl[1], hs2);
    // heads
    heads_kernel<<<8192, 256, 0, stream>>>(hs2, Wa, ba, Wc, bc, action, out);
}

// Round 6
// 273.631 us; speedup vs baseline: 9.4935x; 1.1068x over previous
//
#include <hip/hip_runtime.h>
#include <hip/hip_fp16.h>
#include <stdint.h>

#define B_    64
#define T_    512
#define OBS_  128
#define FEAT_ 512
#define H_    256
#define G_    768
#define BT_   32768
#define NSLOT 16

typedef _Float16 f16x8 __attribute__((ext_vector_type(8)));
typedef float    f32x4 __attribute__((ext_vector_type(4)));

__device__ __forceinline__ uint32_t h2u(__half2 h){ union{ __half2 h; uint32_t u; } c; c.h = h; return c.u; }
__device__ __forceinline__ __half2 u2h(uint32_t u){ union{ uint32_t u; __half2 h; } c; c.u = u; return c.h; }

// swizzled LDS byte offset for GEMM tiles: [128 rows][8 chunks of 16B], chunk ^= row&7
__device__ __forceinline__ int sw(int r, int c) { return r * 128 + ((c ^ (r & 7)) << 4); }

__device__ __forceinline__ uint4 cvt8(float4 a, float4 b) {
    uint4 u;
    u.x = h2u(__floats2half2_rn(a.x, a.y));
    u.y = h2u(__floats2half2_rn(a.z, a.w));
    u.z = h2u(__floats2half2_rn(b.x, b.y));
    u.w = h2u(__floats2half2_rn(b.z, b.w));
    return u;
}

// ---------------------------------------------------------------------------
// MFMA GEMM: C[M x N](fp16) = act( A[M x K] @ W[N x K]^T + bias )
// 128x128 tile, BK=64, 4 waves (2x2), each wave 4x4 frags of 16x16x32_f16.
// (unchanged -- passed r3/r4)
// ---------------------------------------------------------------------------
template<int KD, bool AF32, bool RELU>
__global__ __launch_bounds__(256, 2)
void mfma_gemm(const float* __restrict__ Af, const __half* __restrict__ Ah,
               const __half* __restrict__ Bh, const float* __restrict__ bias,
               uint32_t* __restrict__ C, int N)
{
    __shared__ __align__(16) __half As[128 * 64];
    __shared__ __align__(16) __half Bs[128 * 64];
    const int m0 = blockIdx.x * 128, n0 = blockIdx.y * 128;
    const int tid = threadIdx.x;
    const int r = tid >> 1, cb = (tid & 1) * 4;
    const int lane = tid & 63, w = tid >> 6;
    const int wm = w >> 1, wn = w & 1;
    const int l15 = lane & 15, lq = lane >> 4;
    constexpr int KT = KD / 64;

    f32x4 acc[4][4];
    #pragma unroll
    for (int i = 0; i < 4; ++i)
        #pragma unroll
        for (int j = 0; j < 4; ++j) {
            f32x4 z = {0.f, 0.f, 0.f, 0.f};
            acc[i][j] = z;
        }

    uint4 sa[4], sb[4];
    float4 sa32[8];

    auto loads = [&](int kt) {
        if constexpr (AF32) {
            const float* ap = Af + (size_t)(m0 + r) * KD + kt * 64 + cb * 8;
            #pragma unroll
            for (int c = 0; c < 4; ++c) {
                sa32[2 * c]     = ((const float4*)ap)[2 * c];
                sa32[2 * c + 1] = ((const float4*)ap)[2 * c + 1];
            }
        } else {
            const __half* ap = Ah + (size_t)(m0 + r) * KD + kt * 64 + cb * 8;
            #pragma unroll
            for (int c = 0; c < 4; ++c) sa[c] = ((const uint4*)ap)[c];
        }
        const __half* bp = Bh + (size_t)(n0 + r) * KD + kt * 64 + cb * 8;
        #pragma unroll
        for (int c = 0; c < 4; ++c) sb[c] = ((const uint4*)bp)[c];
    };

    auto dswrite = [&]() {
        #pragma unroll
        for (int c = 0; c < 4; ++c) {
            uint4 va;
            if constexpr (AF32) va = cvt8(sa32[2 * c], sa32[2 * c + 1]);
            else                va = sa[c];
            *(uint4*)((char*)As + sw(r, cb + c)) = va;
            *(uint4*)((char*)Bs + sw(r, cb + c)) = sb[c];
        }
    };

    auto compute = [&]() {
        #pragma unroll
        for (int kc = 0; kc < 2; ++kc) {
            f16x8 af[4], bf[4];
            #pragma unroll
            for (int mi = 0; mi < 4; ++mi)
                af[mi] = *(const f16x8*)((const char*)As + sw(wm * 64 + mi * 16 + l15, kc * 4 + lq));
            #pragma unroll
            for (int ni = 0; ni < 4; ++ni)
                bf[ni] = *(const f16x8*)((const char*)Bs + sw(wn * 64 + ni * 16 + l15, kc * 4 + lq));
            #pragma unroll
            for (int mi = 0; mi < 4; ++mi)
                #pragma unroll
                for (int ni = 0; ni < 4; ++ni)
                    acc[mi][ni] = __builtin_amdgcn_mfma_f32_16x16x32_f16(af[mi], bf[ni], acc[mi][ni], 0, 0, 0);
        }
    };

    loads(0);
    for (int kt = 0; kt < KT; ++kt) {
        __syncthreads();
        dswrite();
        __syncthreads();
        if (kt + 1 < KT) loads(kt + 1);
        compute();
    }

    #pragma unroll
    for (int ni = 0; ni < 4; ++ni) {
        const int col = n0 + wn * 64 + ni * 16 + l15;
        const float bv = bias[col];
        #pragma unroll
        for (int mi = 0; mi < 4; ++mi) {
            f32x4 d = acc[mi][ni];
            #pragma unroll
            for (int rr = 0; rr < 4; ++rr) {
                float v = d[rr] + bv;
                if (RELU) v = fmaxf(v, 0.0f);
                uint32_t u = (uint32_t)__half_as_ushort(__float2half(v));
                uint32_t nb = (uint32_t)__shfl_xor((int)u, 1);
                if (!(lane & 1)) {
                    const int row = m0 + wm * 64 + mi * 16 + lq * 4 + rr;
                    C[(size_t)row * (N >> 1) + (col >> 1)] = u | (nb << 16);
                }
            }
        }
    }
}

// ---------------------------------------------------------------------------
// Weight packs (fp32 -> fp16). pack_whh zeroes qctl (runs before seg_build,
// r4-proven pattern) and emits W_hh in MFMA A-fragment per-lane order:
// lane t=w*64+lane holds rows w*96+i*16+(lane&15), k = c*32+(lane>>4)*8+j.
// ---------------------------------------------------------------------------
__global__ void pack_half(const float* __restrict__ in, uint32_t* __restrict__ out, int n2)
{
    int i = blockIdx.x * 256 + threadIdx.x;
    if (i < n2) {
        float2 f = ((const float2*)in)[i];
        out[i] = h2u(__floats2half2_rn(f.x, f.y));
    }
}

__global__ void pack_whh(const float* __restrict__ Whh, uint32_t* __restrict__ out,
                         int* __restrict__ qctl)
{
    if (blockIdx.x == 0 && threadIdx.x == 0) { qctl[0] = 0; qctl[1] = 0; }
    int p = blockIdx.x * 256 + threadIdx.x;
    if (p >= 512 * 192) return;
    const int v4 = p >> 2, sub = p & 3;
    const int t = v4 / 48, ic = v4 - t * 48;
    const int i = ic >> 3, c = ic & 7;
    const int w = t >> 6, lane = t & 63;
    const int row = w * 96 + i * 16 + (lane & 15);
    const int kb = c * 32 + ((lane >> 4) << 3) + sub * 2;
    out[p] = h2u(__floats2half2_rn(Whh[row * 256 + kb], Whh[row * 256 + kb + 1]));
}

// ---------------------------------------------------------------------------
// Segment builder (r4-proven): masks reset h to 0, so the scan splits into
// independent segments. Queue entry = (b<<19)|(start<<10)|len, compacted;
// valid iff start==0 (h0 seed) or len>=2 (len-1 ones fully done by h0pre).
// ---------------------------------------------------------------------------
__global__ __launch_bounds__(512)
void seg_build(const int* __restrict__ masks, int* __restrict__ queue,
               int* __restrict__ qtail)
{
    __shared__ int sc[512];
    __shared__ int starts[512];
    __shared__ int cshr[2];
    const int b = blockIdx.x, s = threadIdx.x;
    const int is = (s == 0) || (masks[b * (T_ - 1) + s - 1] == 0);
    sc[s] = is;
    __syncthreads();
    #pragma unroll
    for (int off = 1; off < 512; off <<= 1) {
        int v = (s >= off) ? sc[s - off] : 0;
        __syncthreads();
        sc[s] += v;
        __syncthreads();
    }
    if (is) starts[sc[s] - 1] = s;
    if (s == 511) cshr[0] = sc[511];
    __syncthreads();
    const int cnt = cshr[0];
    int valid = 0, st = 0, ln = 0;
    if (s < cnt) {
        st = starts[s];
        const int nxt = (s + 1 < cnt) ? starts[s + 1] : T_;
        ln = nxt - st;
        valid = (st == 0 || ln >= 2) ? 1 : 0;
    }
    sc[s] = valid;
    __syncthreads();
    #pragma unroll
    for (int off = 1; off < 512; off <<= 1) {
        int v = (s >= off) ? sc[s - off] : 0;
        __syncthreads();
        sc[s] += v;
        __syncthreads();
    }
    if (s == 511) cshr[1] = atomicAdd(qtail, sc[511]);
    __syncthreads();
    if (valid) queue[cshr[1] + sc[s] - 1] = (b << 19) | (st << 10) | ln;
}

// ---------------------------------------------------------------------------
// Pre-pass (r4-proven): every step t>=1 with mask==0 has h_prev==0.
// ---------------------------------------------------------------------------
__global__ __launch_bounds__(256)
void h0pre(const __half* __restrict__ gx, const float* __restrict__ bhh,
           const int* __restrict__ masks, uint32_t* __restrict__ hs2)
{
    const int row = blockIdx.x;                 // 0 .. B*(T-1)-1
    if (masks[row] != 0) return;
    const int b = row / (T_ - 1), t = 1 + row - b * (T_ - 1);
    const int e = threadIdx.x;
    const __half* grow = gx + (size_t)(b * T_ + t) * 768;
    const float gxr = __half2float(grow[e]);
    const float gxz = __half2float(grow[e + 256]);
    const float gxn = __half2float(grow[e + 512]);
    const float rg = 1.f / (1.f + exp2f(-(gxr + bhh[e]) * 1.44269504f));
    const float zg = 1.f / (1.f + exp2f(-(gxz + bhh[e + 256]) * 1.44269504f));
    const float nin = gxn + rg * bhh[e + 512];
    const float e2x = exp2f(nin * 2.885390082f);
    const float ng = 1.f - 2.f / (e2x + 1.f);
    const float hnew = (1.f - zg) * ng;         // h_prev = 0
    const float other = __shfl_xor(hnew, 1);
    if (!(e & 1)) hs2[(size_t)(b * T_ + t) * 128 + (e >> 1)] = h2u(__floats2half2_rn(hnew, other));
}

// ---------------------------------------------------------------------------
// MFMA slot-parallel GRU, race-proof phase schedule. 256 blocks x 512 threads
// (1 block/CU), 16 slots/block. Static queue slice per block (no global
// atomics); all slot metadata owned by threads 0..15 in phase A; every LDS
// producer/consumer pair is separated by __syncthreads. W_hh lives in 192
// VGPRs of A-fragments ((512,2) budget=256; (512,4) spilled in r2).
// Per iteration: gh[768x16] = W_hh x H (48 MFMA/wave), gates for 16 steps.
// ---------------------------------------------------------------------------
__global__ __launch_bounds__(512, 2)
void gru_mfma(const __half* __restrict__ gx, const uint32_t* __restrict__ WhhP,
              const float* __restrict__ bhh, const float* __restrict__ h0,
              const int* __restrict__ queue, const int* __restrict__ qctl,
              uint32_t* __restrict__ hs2)
{
    __shared__ __align__(16) __half Hl[NSLOT * 256];   // [slot][k], granule-swizzled
    __shared__ __align__(16) float  Pl[NSLOT * 780];   // [slot][row + pad]
    __shared__ __align__(16) __half GXl[NSLOT * 768];  // [slot][g]
    __shared__ float Bl[G_];
    __shared__ int s_b[NSLOT], s_t[NSLOT], s_end[NSLOT], s_row[NSLOT],
                   s_act[NSLOT], s_need[NSLOT];
    __shared__ int cur;

    const int tid = threadIdx.x;
    const int lane = tid & 63, w = tid >> 6;
    const int s = tid >> 5, g32 = tid & 31, e0 = g32 * 8;
    const int col = lane & 15, lq = lane >> 4;

    // ---- W_hh fragments: 48 contiguous f16x8 per lane (192 VGPR) ----
    f16x8 wfrag[6][8];
    {
        const f16x8* wp = (const f16x8*)(WhhP + (size_t)tid * 192);
        #pragma unroll
        for (int i = 0; i < 6; ++i)
            #pragma unroll
            for (int c = 0; c < 8; ++c)
                wfrag[i][c] = wp[i * 8 + c];
    }
    if (tid < 384) { Bl[tid] = bhh[tid]; Bl[tid + 384] = bhh[tid + 384]; }
    {
        const uint4 z4 = {0u, 0u, 0u, 0u};
        *(uint4*)((char*)Hl + tid * 16) = z4;
    }
    const int NQ = qctl[0];
    const int g = blockIdx.x;
    const int lo = (int)(((long long)NQ * g) >> 8);
    const int hi = (int)(((long long)NQ * (g + 1)) >> 8);
    if (tid == 0) cur = lo;
    if (tid < NSLOT) {
        s_act[tid] = 1; s_t[tid] = 0; s_end[tid] = 0;
        s_row[tid] = 0; s_need[tid] = 0; s_b[tid] = 0;
    }
    __syncthreads();

    float hv[8] = {0.f, 0.f, 0.f, 0.f, 0.f, 0.f, 0.f, 0.f};

    for (;;) {
        // ---- phase A: slot metadata, one thread per slot ----
        if (tid < NSLOT) {
            s_need[tid] = 0;
            if (s_act[tid]) {
                if (s_t[tid] + 1 < s_end[tid]) { s_t[tid]++; s_row[tid]++; }
                else {
                    const int p = atomicAdd(&cur, 1);      // LDS atomic, block-local
                    if (p < hi) {
                        const int en = queue[p];
                        const int ln = en & 1023, st = (en >> 10) & 511, nb = en >> 19;
                        s_b[tid] = nb; s_need[tid] = 1;
                        if (st == 0) { s_t[tid] = 0;      s_end[tid] = ln;      s_row[tid] = nb * T_; }
                        else         { s_t[tid] = st + 1; s_end[tid] = st + ln; s_row[tid] = nb * T_ + st + 1; }
                    } else {
                        s_act[tid] = 0;
                    }
                }
            }
        }
        __syncthreads();
        bool alive = false;
        #pragma unroll
        for (int i = 0; i < NSLOT; ++i) alive |= (s_act[i] != 0);
        if (!alive) break;

        // ---- phase B: seed refilled slots (group s owns slot s) ----
        if (s_need[s]) {
            uint4 hseed;
            if (s_t[s] == 0) {                           // batch-initial: h from h0
                const float4 a = *(const float4*)(h0 + s_b[s] * 256 + e0);
                const float4 b = *(const float4*)(h0 + s_b[s] * 256 + e0 + 4);
                hv[0] = a.x; hv[1] = a.y; hv[2] = a.z; hv[3] = a.w;
                hv[4] = b.x; hv[5] = b.y; hv[6] = b.z; hv[7] = b.w;
                hseed = cvt8(a, b);
            } else {                                     // seed = h0pre output at start step
                hseed = *(const uint4*)(hs2 + (size_t)(s_row[s] - 1) * 128 + g32 * 4);
                const __half2 p0 = u2h(hseed.x), p1 = u2h(hseed.y);
                const __half2 p2 = u2h(hseed.z), p3 = u2h(hseed.w);
                hv[0] = __low2float(p0); hv[1] = __high2float(p0);
                hv[2] = __low2float(p1); hv[3] = __high2float(p1);
                hv[4] = __low2float(p2); hv[5] = __high2float(p2);
                hv[6] = __low2float(p3); hv[7] = __high2float(p3);
            }
            *(uint4*)((char*)Hl + s * 512 + ((g32 ^ (s & 7)) << 4)) = hseed;
        }
        __syncthreads();

        // ---- phase C: gx prefetch || MFMA gh = W_hh x H || land in LDS ----
        uint4 gv[3];
        int gs_[3], go_[3];
        #pragma unroll
        for (int rep = 0; rep < 3; ++rep) {
            const int li = tid + 512 * rep;              // [16 slots][96 uint4]
            gs_[rep] = li / 96;
            go_[rep] = li - gs_[rep] * 96;
            gv[rep] = *(const uint4*)(gx + (size_t)s_row[gs_[rep]] * G_ + go_[rep] * 8);
        }
        f32x4 acc[6];
        #pragma unroll
        for (int i = 0; i < 6; ++i) { f32x4 z = {0.f, 0.f, 0.f, 0.f}; acc[i] = z; }
        #pragma unroll
        for (int c = 0; c < 8; ++c) {
            const f16x8 bf = *(const f16x8*)((const char*)Hl + col * 512 +
                                             ((((c << 2) + lq) ^ (col & 7)) << 4));
            #pragma unroll
            for (int i = 0; i < 6; ++i)
                acc[i] = __builtin_amdgcn_mfma_f32_16x16x32_f16(wfrag[i][c], bf, acc[i], 0, 0, 0);
        }
        #pragma unroll
        for (int i = 0; i < 6; ++i)
            *(f32x4*)(Pl + col * 780 + (w * 96 + i * 16 + lq * 4)) = acc[i];
        #pragma unroll
        for (int rep = 0; rep < 3; ++rep)
            *(uint4*)(GXl + gs_[rep] * G_ + go_[rep] * 8) = gv[rep];
        __syncthreads();

        // ---- phase D: gates (pure compute; no metadata writes) ----
        if (s_act[s]) {
            const float* Pr = Pl + s * 780;
            const f32x4 R0 = *(const f32x4*)(Pr + e0),       R1 = *(const f32x4*)(Pr + e0 + 4);
            const f32x4 Z0 = *(const f32x4*)(Pr + 256 + e0), Z1 = *(const f32x4*)(Pr + 256 + e0 + 4);
            const f32x4 N0 = *(const f32x4*)(Pr + 512 + e0), N1 = *(const f32x4*)(Pr + 512 + e0 + 4);
            const f32x4 br0 = *(const f32x4*)(Bl + e0),       br1 = *(const f32x4*)(Bl + e0 + 4);
            const f32x4 bz0 = *(const f32x4*)(Bl + 256 + e0), bz1 = *(const f32x4*)(Bl + 256 + e0 + 4);
            const f32x4 bn0 = *(const f32x4*)(Bl + 512 + e0), bn1 = *(const f32x4*)(Bl + 512 + e0 + 4);
            const f16x8 gr = *(const f16x8*)(GXl + s * G_ + e0);
            const f16x8 gz = *(const f16x8*)(GXl + s * G_ + 256 + e0);
            const f16x8 gn = *(const f16x8*)(GXl + s * G_ + 512 + e0);
            float hn[8];
            #pragma unroll
            for (int j = 0; j < 8; ++j) {
                const float ghr = (j < 4 ? R0[j] : R1[j - 4]) + (j < 4 ? br0[j] : br1[j - 4]);
                const float ghz = (j < 4 ? Z0[j] : Z1[j - 4]) + (j < 4 ? bz0[j] : bz1[j - 4]);
                const float ghn = (j < 4 ? N0[j] : N1[j - 4]) + (j < 4 ? bn0[j] : bn1[j - 4]);
                const float rg = 1.f / (1.f + exp2f(-((float)gr[j] + ghr) * 1.44269504f));
                const float zg = 1.f / (1.f + exp2f(-((float)gz[j] + ghz) * 1.44269504f));
                const float nin = (float)gn[j] + rg * ghn;
                const float ex = exp2f(nin * 2.885390082f);
                const float ng = 1.f - 2.f / (ex + 1.f);
                hn[j] = (1.f - zg) * ng + zg * hv[j];
                hv[j] = hn[j];
            }
            uint4 hp;
            hp.x = h2u(__floats2half2_rn(hn[0], hn[1]));
            hp.y = h2u(__floats2half2_rn(hn[2], hn[3]));
            hp.z = h2u(__floats2half2_rn(hn[4], hn[5]));
            hp.w = h2u(__floats2half2_rn(hn[6], hn[7]));
            *(uint4*)(hs2 + (size_t)s_row[s] * 128 + g32 * 4) = hp;
            *(uint4*)((char*)Hl + s * 512 + ((g32 ^ (s & 7)) << 4)) = hp;
        }
        __syncthreads();
    }
}

// ---------------------------------------------------------------------------
// Heads (unchanged): one wave per output row, hs fp16.
// ---------------------------------------------------------------------------
__global__ __launch_bounds__(256)
void heads_kernel(const uint32_t* __restrict__ hs2, const float* __restrict__ Wa,
                  const float* __restrict__ ba, const float* __restrict__ Wc,
                  const float* __restrict__ bc, const int* __restrict__ action,
                  float* __restrict__ out)
{
    const int wid = threadIdx.x >> 6, lane = threadIdx.x & 63;
    const int row = blockIdx.x * 4 + wid;
    const uint2 hv2 = ((const uint2*)(hs2 + (size_t)row * 128))[lane];
    const __half2 ha = u2h(hv2.x), hb = u2h(hv2.y);
    const float h0f = __low2float(ha), h1f = __high2float(ha);
    const float h2f = __low2float(hb), h3f = __high2float(hb);
    float sums[11];
    #pragma unroll
    for (int n = 0; n < 11; ++n) {
        const float* wrow = (n < 10) ? (Wa + n * 256) : Wc;
        const float4 wv = ((const float4*)wrow)[lane];
        sums[n] = h0f * wv.x + h1f * wv.y + h2f * wv.z + h3f * wv.w;
    }
    #pragma unroll
    for (int n = 0; n < 11; ++n) {
        float v = sums[n];
        #pragma unroll
        for (int off = 32; off; off >>= 1) v += __shfl_xor(v, off);
        sums[n] = v;
    }
    float logits[10];
    #pragma unroll
    for (int n = 0; n < 10; ++n) logits[n] = sums[n] + ba[n];
    const float value = sums[10] + bc[0];
    float mx = logits[0];
    #pragma unroll
    for (int n = 1; n < 10; ++n) mx = fmaxf(mx, logits[n]);
    float ssum = 0.f, sdot = 0.f;
    #pragma unroll
    for (int n = 0; n < 10; ++n) {
        float d = logits[n] - mx;
        float e = exp2f(d * 1.44269504f);
        ssum += e; sdot += e * d;
    }
    const float lns = logf(ssum);
    const float lse = mx + lns;
    const float entropy = lns - sdot / ssum;
    const int a = action[row];
    float la = 0.f;
    #pragma unroll
    for (int n = 0; n < 10; ++n) la = (n == a) ? logits[n] : la;
    if (lane == 0) {
        out[row] = value;
        out[BT_ + row] = la - lse;
        out[2 * BT_ + row] = entropy;
    }
}

// ---------------------------------------------------------------------------
extern "C" void kernel_launch(void* const* d_in, const int* in_sizes, int n_in,
                              void* d_out, int out_size, void* d_ws, size_t ws_size,
                              hipStream_t stream)
{
    const float* obs    = (const float*)d_in[0];
    const int*   action = (const int*)d_in[1];
    const int*   masks  = (const int*)d_in[2];
    const float* h0     = (const float*)d_in[3];
    const float* W1     = (const float*)d_in[4];
    const float* b1     = (const float*)d_in[5];
    const float* Wih    = (const float*)d_in[6];
    const float* Whh    = (const float*)d_in[7];
    const float* bih    = (const float*)d_in[8];
    const float* bhh    = (const float*)d_in[9];
    const float* Wa     = (const float*)d_in[10];
    const float* ba     = (const float*)d_in[11];
    const float* Wc     = (const float*)d_in[12];
    const float* bc     = (const float*)d_in[13];
    float* out = (float*)d_out;

    char* p = (char*)d_ws;
    __half*   feat = (__half*)p;    p += (size_t)BT_ * FEAT_ * 2;   // 33.6 MB
    __half*   gx   = (__half*)p;    p += (size_t)BT_ * G_ * 2;      // 50.3 MB
    uint32_t* hs2  = (uint32_t*)p;  p += (size_t)BT_ * H_ * 2;      // 16.8 MB
    uint32_t* W1h  = (uint32_t*)p;  p += FEAT_ * OBS_ * 2;          // 131 KB
    uint32_t* Wihh = (uint32_t*)p;  p += G_ * FEAT_ * 2;            // 786 KB
    uint32_t* WhhP = (uint32_t*)p;  p += 512 * 192 * 4;             // 393 KB
    int*      queue= (int*)p;       p += B_ * 512 * 4;              // 131 KB
    int*      qctl = (int*)p;       p += 256;                       // [0]=tail

    // packs (pack_whh zeroes qctl) + segment queue build
    pack_half<<<(FEAT_ * OBS_ / 2 + 255) / 256, 256, 0, stream>>>(W1, W1h, FEAT_ * OBS_ / 2);
    pack_half<<<(G_ * FEAT_ / 2 + 255) / 256, 256, 0, stream>>>(Wih, Wihh, G_ * FEAT_ / 2);
    pack_whh<<<384, 256, 0, stream>>>(Whh, WhhP, qctl);
    seg_build<<<B_, 512, 0, stream>>>(masks, queue, &qctl[0]);
    // feat = relu(obs @ W1^T + b1)
    mfma_gemm<OBS_, true, true><<<dim3(256, 4), 256, 0, stream>>>(obs, nullptr, (const __half*)W1h, b1, (uint32_t*)feat, FEAT_);
    // gx = feat @ W_ih^T + b_ih   (batch-major rows)
    mfma_gemm<FEAT_, false, false><<<dim3(256, 6), 256, 0, stream>>>(nullptr, feat, (const __half*)Wihh, bih, (uint32_t*)gx, G_);
    // pre-pass: all h_prev==0 steps (elementwise)
    h0pre<<<B_ * (T_ - 1), 256, 0, stream>>>(gx, bhh, masks, hs2);
    // MFMA slot-parallel recurrence (static queue slices, phase-barriered)
    gru_mfma<<<256, 512, 0, stream>>>(gx, WhhP, bhh, h0, queue, qctl, hs2);
    // heads
    heads_kernel<<<8192, 256, 0, stream>>>(hs2, Wa, ba, Wc, bc, action, out);
}